// Round 5
// baseline (6643.741 us; speedup 1.0000x reference)
//
#include <hip/hip_runtime.h>
#include <hip/hip_bf16.h>

#define N_NODES 50000
#define N_EDGES 800000
#define D 128
#define N_ETYPES 4
#define N_STEPS 8
#define B_GRAPHS 50
#define HID 256
#define POOL_SPLIT 16
#define SCAN_B 196  // ceil(50000/256)

typedef __attribute__((ext_vector_type(8))) short short8;
typedef __attribute__((ext_vector_type(4))) float f32x4;
typedef __attribute__((ext_vector_type(4))) unsigned uint4v;

static __device__ __forceinline__ unsigned short f2bf(float f) {
    union { float f; unsigned u; } v; v.f = f;
    unsigned r = v.u + 0x7FFF + ((v.u >> 16) & 1);
    return (unsigned short)(r >> 16);
}
static __device__ __forceinline__ unsigned pk2(float a, float b) {
    return (unsigned)f2bf(a) | ((unsigned)f2bf(b) << 16);
}
static __device__ __forceinline__ float bf2f_u(unsigned s) {  // low 16 bits
    union { unsigned u; float f; } v; v.u = s << 16;
    return v.f;
}
static __device__ __forceinline__ float fsigmoid(float x) {
    return 1.f / (1.f + __expf(-x));
}
static __device__ __forceinline__ float ftanh(float x) {
    return 2.f / (1.f + __expf(-2.f * x)) - 1.f;
}
static __device__ __forceinline__ void gload_lds16(const void* g, void* lds) {
    __builtin_amdgcn_global_load_lds(
        (const __attribute__((address_space(1))) unsigned char*)g,
        (__attribute__((address_space(3))) unsigned char*)lds, 16, 0, 0);
}

// ---- 30-phase schedule helpers (constexpr-folded under #pragma unroll) ----
// gates 0,1 (r,z): q0..7 = S-part (kc=2q,2q+1), q8..9 = h-part (c=2(q-8),+1)
// gate 2 (n):      q0..1 = h-part (Gh), q2..9 = S-part (Gi)
__host__ __device__ constexpr bool ph_is_s(int i) {
    return (i / 10) < 2 ? (i % 10) < 8 : (i % 10) >= 2;
}
__host__ __device__ constexpr int ph_kcs(int i) {
    return (i / 10) < 2 ? 2 * (i % 10) : 2 * ((i % 10) - 2);
}
__host__ __device__ constexpr int ph_hcb(int i) {
    return (i / 10) < 2 ? 2 * ((i % 10) - 8) : 2 * (i % 10);
}
__host__ __device__ constexpr int ph_off(int i) {
    return ph_is_s(i) ? ph_kcs(i) : 16 + ph_hcb(i);
}

// ---------------- init: h_bf = bf16(node_features) ----------------
__global__ void k_init_h(const float* __restrict__ nf, unsigned short* __restrict__ hbf) {
    int i = blockIdx.x * blockDim.x + threadIdx.x;
    if (i < N_NODES * D) hbf[i] = f2bf(nf[i]);
}

// ---------------- CSR build ----------------
__global__ void k_hist(const int* __restrict__ dst, int* __restrict__ deg) {
    int e = blockIdx.x * blockDim.x + threadIdx.x;
    if (e < N_EDGES) atomicAdd(&deg[dst[e]], 1);
}

__global__ __launch_bounds__(256) void k_scan1(const int* __restrict__ deg,
                                               int* __restrict__ bsum) {
    __shared__ int tmp[256];
    int t = threadIdx.x;
    int i = blockIdx.x * 256 + t;
    tmp[t] = (i < N_NODES) ? deg[i] : 0;
    __syncthreads();
    for (int s = 128; s > 0; s >>= 1) {
        if (t < s) tmp[t] += tmp[t + s];
        __syncthreads();
    }
    if (t == 0) bsum[blockIdx.x] = tmp[0];
}

__global__ __launch_bounds__(256) void k_scan2(const int* __restrict__ bsum,
                                               int* __restrict__ bpfx,
                                               int* __restrict__ rowptr) {
    __shared__ int part[256];
    int t = threadIdx.x;
    int v = (t < SCAN_B) ? bsum[t] : 0;
    part[t] = v;
    __syncthreads();
    for (int off = 1; off < 256; off <<= 1) {
        int u = (t >= off) ? part[t - off] : 0;
        __syncthreads();
        part[t] += u;
        __syncthreads();
    }
    if (t < SCAN_B) bpfx[t] = part[t] - v;  // exclusive
    if (t == SCAN_B - 1) rowptr[N_NODES] = part[t];
}

__global__ __launch_bounds__(256) void k_scan3(const int* __restrict__ deg,
                                               const int* __restrict__ bpfx,
                                               int* __restrict__ rowptr,
                                               int* __restrict__ cursor) {
    __shared__ int part[256];
    int t = threadIdx.x;
    int i = blockIdx.x * 256 + t;
    int v = (i < N_NODES) ? deg[i] : 0;
    part[t] = v;
    __syncthreads();
    for (int off = 1; off < 256; off <<= 1) {
        int u = (t >= off) ? part[t - off] : 0;
        __syncthreads();
        part[t] += u;
        __syncthreads();
    }
    if (i < N_NODES) {
        int rp = bpfx[blockIdx.x] + part[t] - v;
        rowptr[i] = rp;
        cursor[i] = rp;
    }
}

__global__ void k_fill(const int* __restrict__ src, const int* __restrict__ dst,
                       const int* __restrict__ et, int* __restrict__ cursor,
                       int* __restrict__ epack) {
    int e = blockIdx.x * blockDim.x + threadIdx.x;
    if (e < N_EDGES) {
        int slot = atomicAdd(&cursor[dst[e]], 1);
        epack[slot] = src[e] | (et[e] << 16);  // src < 50000 < 2^16
    }
}

// ---------------- pack PW = [Wbig ; Whh-slices] in MFMA B-frag layout -------
// frag f = (p*8+nt)*20 + kc, p<3 gate, nt<8 (gate-local ntile), kc<20 (K=640)
// kc<16:  B[k][n] = Wbig[k][p*128+n] = sum_m Wstack[k][m]*Wih[(p*128+n)][m]
//         Wstack[k][m] = Wmsg[k>>7][(k&127)*128+m],  k = kc*32+(l>>4)*8+i
// kc>=16: B[k'][n] = Whh[(p*128+n)][k'],  k' = (kc-16)*32+(l>>4)*8+i
__global__ void k_pack_pw(const float* __restrict__ Wmsg, const float* __restrict__ Wih,
                          const float* __restrict__ Whh, unsigned short* __restrict__ PW) {
    int f = blockIdx.x;       // 0..479
    int l = threadIdx.x;      // 0..63
    int pnt = f / 20, kc = f % 20;
    int p = pnt >> 3, nt = pnt & 7;
    int ncol = nt * 16 + (l & 15);
    int wr = p * 128 + ncol;
    unsigned short* out = PW + ((size_t)f * 64 + l) * 8;
    if (kc < 16) {
        const float* wi = Wih + (size_t)wr * D;
#pragma unroll
        for (int i = 0; i < 8; ++i) {
            int k = kc * 32 + ((l >> 4) << 3) + i;
            const float* wm = Wmsg + (size_t)(k >> 7) * (D * D) + (size_t)(k & 127) * D;
            float s0 = 0.f, s1 = 0.f;
            for (int m = 0; m < D; m += 2) { s0 += wm[m] * wi[m]; s1 += wm[m + 1] * wi[m + 1]; }
            out[i] = f2bf(s0 + s1);
        }
    } else {
#pragma unroll
        for (int i = 0; i < 8; ++i) {
            int kp = (kc - 16) * 32 + ((l >> 4) << 3) + i;
            out[i] = f2bf(Whh[(size_t)wr * D + kp]);
        }
    }
}

// ---------------- pack bias tables ----------------
// Tb4[p*128+col] = { sum_m bmsg[t*128+m]*Wih[(p*128+col)*128+m] }_{t=0..3}
// bc[p*128+col]  = bih[p*128+col] + (p<2 ? bhh[p*128+col] : 0)
// bhn[col]       = bhh[256+col]
__global__ void k_pack_tb(const float* __restrict__ bmsg, const float* __restrict__ Wih,
                          const float* __restrict__ bih, const float* __restrict__ bhh,
                          float4* __restrict__ Tb4, float* __restrict__ bc,
                          float* __restrict__ bhn) {
    int t = blockIdx.x * blockDim.x + threadIdx.x;
    if (t >= 384) return;
    int p = t >> 7, col = t & 127;
    const float* wi = Wih + (size_t)t * D;
    float s0 = 0.f, s1 = 0.f, s2 = 0.f, s3 = 0.f;
    for (int m = 0; m < D; ++m) {
        float w = wi[m];
        s0 += bmsg[m] * w; s1 += bmsg[128 + m] * w;
        s2 += bmsg[256 + m] * w; s3 += bmsg[384 + m] * w;
    }
    float4 r; r.x = s0; r.y = s1; r.z = s2; r.w = s3;
    Tb4[t] = r;
    bc[t] = bih[t] + (p < 2 ? bhh[t] : 0.f);
    if (p == 2) bhn[col] = bhh[256 + col];
}

// ---------------- aggregate: S[v][t][d] = sum_{in-edges of type t} hbf[src][d] --
__global__ __launch_bounds__(256) void k_aggregate_s(const unsigned short* __restrict__ hbf,
                                                     const int* __restrict__ rowptr,
                                                     const int* __restrict__ epack,
                                                     unsigned short* __restrict__ S,
                                                     unsigned* __restrict__ deg4) {
    int w = threadIdx.x >> 6, l = threadIdx.x & 63;
    int v = blockIdx.x * 4 + w;
    if (v >= N_NODES) return;
    int lo = rowptr[v], hi = rowptr[v + 1];
    float a00 = 0.f, a01 = 0.f, a10 = 0.f, a11 = 0.f;
    float a20 = 0.f, a21 = 0.f, a30 = 0.f, a31 = 0.f;
    unsigned c0 = 0, c1 = 0, c2 = 0, c3 = 0;
    int i = lo;
    for (; i + 4 <= hi; i += 4) {
        int e0 = epack[i], e1 = epack[i + 1], e2 = epack[i + 2], e3 = epack[i + 3];
        unsigned x0 = *(const unsigned*)(hbf + ((size_t)(e0 & 0xFFFF) << 7) + 2 * l);
        unsigned x1 = *(const unsigned*)(hbf + ((size_t)(e1 & 0xFFFF) << 7) + 2 * l);
        unsigned x2 = *(const unsigned*)(hbf + ((size_t)(e2 & 0xFFFF) << 7) + 2 * l);
        unsigned x3 = *(const unsigned*)(hbf + ((size_t)(e3 & 0xFFFF) << 7) + 2 * l);
#define ACC_EDGE(e, x)                                                        \
        {                                                                     \
            int t_ = (e) >> 16;                                               \
            float lo_ = bf2f_u((x) & 0xFFFF), hi_ = bf2f_u((x) >> 16);        \
            if (t_ == 0)      { a00 += lo_; a01 += hi_; c0++; }               \
            else if (t_ == 1) { a10 += lo_; a11 += hi_; c1++; }               \
            else if (t_ == 2) { a20 += lo_; a21 += hi_; c2++; }               \
            else              { a30 += lo_; a31 += hi_; c3++; }               \
        }
        ACC_EDGE(e0, x0) ACC_EDGE(e1, x1) ACC_EDGE(e2, x2) ACC_EDGE(e3, x3)
    }
    for (; i < hi; ++i) {
        int e0 = epack[i];
        unsigned x0 = *(const unsigned*)(hbf + ((size_t)(e0 & 0xFFFF) << 7) + 2 * l);
        ACC_EDGE(e0, x0)
    }
#undef ACC_EDGE
    unsigned* Srow = (unsigned*)(S + (size_t)v * 512);
    Srow[l]       = (unsigned)f2bf(a00) | ((unsigned)f2bf(a01) << 16);
    Srow[64 + l]  = (unsigned)f2bf(a10) | ((unsigned)f2bf(a11) << 16);
    Srow[128 + l] = (unsigned)f2bf(a20) | ((unsigned)f2bf(a21) << 16);
    Srow[192 + l] = (unsigned)f2bf(a30) | ((unsigned)f2bf(a31) << 16);
    if (l == 0) {
        uint4v dg = {c0, c1, c2, c3};
        *(uint4v*)(deg4 + (size_t)v * 4) = dg;
    }
}

// ---------------- fused GRU: gi = S@Wbig(+dg-bias), gh = h@Whh^T, update h --
// 64 rows/block (4 waves x 16). 30 phases x 16 KB staging, 3-deep LDS rotation,
// ONE raw s_barrier per phase, counted vmcnt (never 0 in steady state).
#define STAGE(ph, slot)                                                        \
    { _Pragma("unroll")                                                        \
      for (int j_ = 0; j_ < 4; ++j_) {                                         \
          int ci_ = j_ * 4 + w;                                                \
          int nt_ = ci_ >> 1, s_ = ci_ & 1;                                    \
          int fid_ = (((ph) / 10) * 8 + nt_) * 20 + ph_off(ph) + s_;           \
          gload_lds16(PW + ((size_t)fid_ * 64 + l) * 8, &Bs[(slot)][ci_ * 512]); \
      } }

__global__ __launch_bounds__(256, 3) void k_gru_fused(
        const unsigned short* __restrict__ S,
        unsigned short* __restrict__ hbf,
        const unsigned short* __restrict__ PW,
        const unsigned* __restrict__ deg4,
        const float4* __restrict__ Tb4,
        const float* __restrict__ bc,
        const float* __restrict__ bhn) {
    __shared__ unsigned short Bs[3][16 * 512];  // 3 x 16 KB
    int tid = threadIdx.x, w = tid >> 6, l = tid & 63;
    int lr = l & 15, kb = l >> 4;
    int base = blockIdx.x * 64 + w * 16;
    int arow = base + lr; if (arow >= N_NODES) arow = N_NODES - 1;
    const short8* Sr = (const short8*)(S + (size_t)arow * 512);
    const short8* hr = (const short8*)(hbf + (size_t)arow * D);
    short8 afh[4];
#pragma unroll
    for (int c = 0; c < 4; ++c) afh[c] = hr[c * 4 + kb];
    STAGE(0, 0);
    short8 sA = Sr[0 * 4 + kb], sB = Sr[1 * 4 + kb];  // phase 0: kc 0,1
    f32x4 acc[8];
#pragma unroll
    for (int nt = 0; nt < 8; ++nt) acc[nt] = (f32x4){0.f, 0.f, 0.f, 0.f};
    unsigned rpk[8][2], zpk[8][2], ghpk[8][2];
#pragma unroll
    for (int i = 0; i < 30; ++i) {
        const int slot = i % 3, nslot = (i + 1) % 3;
        if (i < 29) STAGE(i + 1, nslot);
        short8 sAn, sBn;
        if (i < 29 && ph_is_s(i + 1)) {
            sAn = Sr[ph_kcs(i + 1) * 4 + kb];
            sBn = Sr[(ph_kcs(i + 1) + 1) * 4 + kb];
        }
        // counted wait: drain everything older than this phase's (4|6) issues
        if (i == 29)                 { asm volatile("s_waitcnt vmcnt(0)" ::: "memory"); }
        else if (ph_is_s(i + 1))     { asm volatile("s_waitcnt vmcnt(6)" ::: "memory"); }
        else                         { asm volatile("s_waitcnt vmcnt(4)" ::: "memory"); }
        __builtin_amdgcn_sched_barrier(0);
        __builtin_amdgcn_s_barrier();
#pragma unroll
        for (int nt = 0; nt < 8; ++nt) {
            short8 b0 = *(const short8*)(&Bs[slot][(nt * 2 + 0) * 512 + l * 8]);
            short8 b1 = *(const short8*)(&Bs[slot][(nt * 2 + 1) * 512 + l * 8]);
            short8 a0, a1;
            if (ph_is_s(i)) { a0 = sA; a1 = sB; }
            else            { a0 = afh[ph_hcb(i)]; a1 = afh[ph_hcb(i) + 1]; }
            acc[nt] = __builtin_amdgcn_mfma_f32_16x16x32_bf16(a0, b0, acc[nt], 0, 0, 0);
            acc[nt] = __builtin_amdgcn_mfma_f32_16x16x32_bf16(a1, b1, acc[nt], 0, 0, 0);
        }
        if (i < 29 && ph_is_s(i + 1)) { sA = sAn; sB = sBn; }
        const int gate = i / 10, q = i % 10;
        if (gate < 2 && q == 9) {  // r / z epilogue
            uint4v dg[4];
#pragma unroll
            for (int j = 0; j < 4; ++j) {
                int row = base + kb * 4 + j; if (row >= N_NODES) row = N_NODES - 1;
                dg[j] = *(const uint4v*)(deg4 + (size_t)row * 4);
            }
#pragma unroll
            for (int nt = 0; nt < 8; ++nt) {
                int colL = nt * 16 + lr;
                float4 t4 = Tb4[gate * 128 + colL];
                float bcv = bc[gate * 128 + colL];
                float v0, v1, v2, v3;
                {
                    float G0 = acc[nt][0] + (float)dg[0].x * t4.x + (float)dg[0].y * t4.y + (float)dg[0].z * t4.z + (float)dg[0].w * t4.w + bcv;
                    float G1 = acc[nt][1] + (float)dg[1].x * t4.x + (float)dg[1].y * t4.y + (float)dg[1].z * t4.z + (float)dg[1].w * t4.w + bcv;
                    float G2 = acc[nt][2] + (float)dg[2].x * t4.x + (float)dg[2].y * t4.y + (float)dg[2].z * t4.z + (float)dg[2].w * t4.w + bcv;
                    float G3 = acc[nt][3] + (float)dg[3].x * t4.x + (float)dg[3].y * t4.y + (float)dg[3].z * t4.z + (float)dg[3].w * t4.w + bcv;
                    v0 = fsigmoid(G0); v1 = fsigmoid(G1); v2 = fsigmoid(G2); v3 = fsigmoid(G3);
                }
                if (gate == 0) { rpk[nt][0] = pk2(v0, v1); rpk[nt][1] = pk2(v2, v3); }
                else           { zpk[nt][0] = pk2(v0, v1); zpk[nt][1] = pk2(v2, v3); }
                acc[nt] = (f32x4){0.f, 0.f, 0.f, 0.f};
            }
        }
        if (gate == 2 && q == 1) {  // Gh finalize (pre r-multiply)
#pragma unroll
            for (int nt = 0; nt < 8; ++nt) {
                int colL = nt * 16 + lr;
                float bh = bhn[colL];
                ghpk[nt][0] = pk2(acc[nt][0] + bh, acc[nt][1] + bh);
                ghpk[nt][1] = pk2(acc[nt][2] + bh, acc[nt][3] + bh);
                acc[nt] = (f32x4){0.f, 0.f, 0.f, 0.f};
            }
        }
        if (i == 29) {  // n-gate + h update
            uint4v dg[4];
#pragma unroll
            for (int j = 0; j < 4; ++j) {
                int row = base + kb * 4 + j; if (row >= N_NODES) row = N_NODES - 1;
                dg[j] = *(const uint4v*)(deg4 + (size_t)row * 4);
            }
#pragma unroll
            for (int nt = 0; nt < 8; ++nt) {
                int colL = nt * 16 + lr;
                float4 t4 = Tb4[256 + colL];
                float bcv = bc[256 + colL];
#pragma unroll
                for (int j = 0; j < 4; ++j) {
                    int row = base + kb * 4 + j;
                    if (row < N_NODES) {
                        float Gi = acc[nt][j] + (float)dg[j].x * t4.x + (float)dg[j].y * t4.y +
                                   (float)dg[j].z * t4.z + (float)dg[j].w * t4.w + bcv;
                        float Gh = bf2f_u((ghpk[nt][j >> 1] >> (16 * (j & 1))) & 0xFFFF);
                        float r  = bf2f_u((rpk[nt][j >> 1] >> (16 * (j & 1))) & 0xFFFF);
                        float z  = bf2f_u((zpk[nt][j >> 1] >> (16 * (j & 1))) & 0xFFFF);
                        float nn = ftanh(Gi + r * Gh);
                        size_t idx = (size_t)row * D + colL;
                        float hold = bf2f_u(hbf[idx]);
                        hbf[idx] = f2bf((1.f - z) * nn + z * hold);
                    }
                }
            }
        }
    }
}

// ---------------- pool phase 1: partial row-sums (bf16 h) ----------------
__global__ __launch_bounds__(256) void k_pool1(const unsigned short* __restrict__ hbf,
                                               const int* __restrict__ counts,
                                               float* __restrict__ partial) {
    __shared__ float tmp[256];
    int g = blockIdx.x / POOL_SPLIT;
    int j = blockIdx.x % POOL_SPLIT;
    int t = threadIdx.x;
    int offset = 0;
    for (int i = 0; i < g; ++i) offset += counts[i];
    int cnt = counts[g];
    int d = t & 127, half = t >> 7;
    float acc = 0.f;
    for (int r = 2 * j + half; r < cnt; r += 2 * POOL_SPLIT)
        acc += bf2f_u(hbf[(size_t)(offset + r) * D + d]);
    tmp[t] = acc;
    __syncthreads();
    if (t < D) partial[(size_t)(g * POOL_SPLIT + j) * D + t] = tmp[t] + tmp[t + 128];
}

// ---------------- pool phase 2: combine + MLP + sigmoid ----------------
__global__ __launch_bounds__(256) void k_pool2(const float* __restrict__ partial,
                                               const int* __restrict__ counts,
                                               const float* __restrict__ W1,
                                               const float* __restrict__ b1,
                                               const float* __restrict__ W2,
                                               const float* __restrict__ b2,
                                               float* __restrict__ out) {
    __shared__ float pooled[D];
    __shared__ float xh[HID];
    int g = blockIdx.x;
    int t = threadIdx.x;
    int cnt = counts[g];
    if (t < D) {
        float s = 0.f;
#pragma unroll
        for (int j = 0; j < POOL_SPLIT; ++j)
            s += partial[(size_t)(g * POOL_SPLIT + j) * D + t];
        pooled[t] = s / (float)cnt;
    }
    __syncthreads();
    float x = b1[t];
    for (int k = 0; k < D; ++k) x += pooled[k] * W1[k * HID + t];
    x = fmaxf(x, 0.f);
    xh[t] = x * W2[t];
    __syncthreads();
    for (int s = 128; s > 0; s >>= 1) {
        if (t < s) xh[t] += xh[t + s];
        __syncthreads();
    }
    if (t == 0) out[g] = 1.f / (1.f + __expf(-(xh[0] + b2[0])));
}

extern "C" void kernel_launch(void* const* d_in, const int* in_sizes, int n_in,
                              void* d_out, int out_size, void* d_ws, size_t ws_size,
                              hipStream_t stream) {
    const float* nf   = (const float*)d_in[0];
    const int* esrc   = (const int*)d_in[1];
    const int* edst   = (const int*)d_in[2];
    const int* etyp   = (const int*)d_in[3];
    const int* counts = (const int*)d_in[4];
    const float* Wmsg = (const float*)d_in[5];
    const float* bmsg = (const float*)d_in[6];   // [4][128] flat == [512] concat
    const float* Wih  = (const float*)d_in[7];
    const float* Whh  = (const float*)d_in[8];
    const float* bih  = (const float*)d_in[9];
    const float* bhh  = (const float*)d_in[10];
    const float* W1   = (const float*)d_in[11];
    const float* b1   = (const float*)d_in[12];
    const float* W2   = (const float*)d_in[13];
    const float* b2   = (const float*)d_in[14];
    float* out = (float*)d_out;

    char* ws = (char*)d_ws;
    size_t off = 0;
    auto alloc = [&](size_t bytes) {
        void* p = ws + off;
        off = (off + bytes + 255) & ~(size_t)255;
        return p;
    };
    unsigned short* hbf = (unsigned short*)alloc((size_t)N_NODES * D * 2);
    unsigned short* S   = (unsigned short*)alloc((size_t)N_NODES * 512 * 2);
    unsigned short* PW  = (unsigned short*)alloc((size_t)480 * 64 * 8 * 2);
    float* Tb4 = (float*)alloc(3 * 128 * 16);
    float* bc  = (float*)alloc(3 * 128 * 4);
    float* bhn = (float*)alloc(128 * 4);
    int* deg    = (int*)alloc((size_t)N_NODES * 4);
    unsigned* deg4 = (unsigned*)alloc((size_t)N_NODES * 16);
    int* rowptr = (int*)alloc((size_t)(N_NODES + 1) * 4);
    int* cursor = (int*)alloc((size_t)N_NODES * 4);
    int* epack  = (int*)alloc((size_t)N_EDGES * 4);
    float* partial = (float*)alloc((size_t)B_GRAPHS * POOL_SPLIT * D * 4);
    int* bsum = (int*)alloc(SCAN_B * 4);
    int* bpfx = (int*)alloc(SCAN_B * 4);

    hipMemsetAsync(deg, 0, (size_t)N_NODES * 4, stream);
    k_init_h<<<(N_NODES * D) / 256, 256, 0, stream>>>(nf, hbf);
    k_hist<<<N_EDGES / 256, 256, 0, stream>>>(edst, deg);
    k_scan1<<<SCAN_B, 256, 0, stream>>>(deg, bsum);
    k_scan2<<<1, 256, 0, stream>>>(bsum, bpfx, rowptr);
    k_scan3<<<SCAN_B, 256, 0, stream>>>(deg, bpfx, rowptr, cursor);
    k_fill<<<N_EDGES / 256, 256, 0, stream>>>(esrc, edst, etyp, cursor, epack);
    k_pack_pw<<<480, 64, 0, stream>>>(Wmsg, Wih, Whh, PW);
    k_pack_tb<<<2, 192, 0, stream>>>(bmsg, Wih, bih, bhh, (float4*)Tb4, bc, bhn);

    int gru_blocks = (N_NODES + 63) / 64;    // 782
    int agg_blocks = (N_NODES + 3) / 4;      // 12500
    for (int s = 0; s < N_STEPS; ++s) {
        k_aggregate_s<<<agg_blocks, 256, 0, stream>>>(hbf, rowptr, epack, S, deg4);
        k_gru_fused<<<gru_blocks, 256, 0, stream>>>(S, hbf, PW, deg4,
                                                    (const float4*)Tb4, bc, bhn);
    }
    k_pool1<<<B_GRAPHS * POOL_SPLIT, 256, 0, stream>>>(hbf, counts, partial);
    k_pool2<<<B_GRAPHS, 256, 0, stream>>>(partial, counts, W1, b1, W2, b2, out);
}

// Round 6
// 1073.972 us; speedup vs baseline: 6.1861x; 6.1861x over previous
//
#include <hip/hip_runtime.h>
#include <hip/hip_bf16.h>

#define N_NODES 50000
#define N_EDGES 800000
#define D 128
#define N_ETYPES 4
#define N_STEPS 8
#define B_GRAPHS 50
#define HID 256
#define POOL_SPLIT 16
#define SCAN_B 196  // ceil(50000/256)

typedef __attribute__((ext_vector_type(8))) short short8;
typedef __attribute__((ext_vector_type(4))) float f32x4;
typedef __attribute__((ext_vector_type(4))) unsigned uint4v;

static __device__ __forceinline__ unsigned short f2bf(float f) {
    union { float f; unsigned u; } v; v.f = f;
    unsigned r = v.u + 0x7FFF + ((v.u >> 16) & 1);
    return (unsigned short)(r >> 16);
}
static __device__ __forceinline__ float bf2f_u(unsigned s) {  // low 16 bits
    union { unsigned u; float f; } v; v.u = s << 16;
    return v.f;
}
static __device__ __forceinline__ float fsigmoid(float x) {
    return 1.f / (1.f + __expf(-x));
}
static __device__ __forceinline__ float ftanh(float x) {
    return 2.f / (1.f + __expf(-2.f * x)) - 1.f;
}

// ---------------- init: h_bf = bf16(node_features) ----------------
__global__ void k_init_h(const float* __restrict__ nf, unsigned short* __restrict__ hbf) {
    int i = blockIdx.x * blockDim.x + threadIdx.x;
    if (i < N_NODES * D) hbf[i] = f2bf(nf[i]);
}

// ---------------- CSR build ----------------
__global__ void k_hist(const int* __restrict__ dst, int* __restrict__ deg) {
    int e = blockIdx.x * blockDim.x + threadIdx.x;
    if (e < N_EDGES) atomicAdd(&deg[dst[e]], 1);
}

__global__ __launch_bounds__(256) void k_scan1(const int* __restrict__ deg,
                                               int* __restrict__ bsum) {
    __shared__ int tmp[256];
    int t = threadIdx.x;
    int i = blockIdx.x * 256 + t;
    tmp[t] = (i < N_NODES) ? deg[i] : 0;
    __syncthreads();
    for (int s = 128; s > 0; s >>= 1) {
        if (t < s) tmp[t] += tmp[t + s];
        __syncthreads();
    }
    if (t == 0) bsum[blockIdx.x] = tmp[0];
}

__global__ __launch_bounds__(256) void k_scan2(const int* __restrict__ bsum,
                                               int* __restrict__ bpfx,
                                               int* __restrict__ rowptr) {
    __shared__ int part[256];
    int t = threadIdx.x;
    int v = (t < SCAN_B) ? bsum[t] : 0;
    part[t] = v;
    __syncthreads();
    for (int off = 1; off < 256; off <<= 1) {
        int u = (t >= off) ? part[t - off] : 0;
        __syncthreads();
        part[t] += u;
        __syncthreads();
    }
    if (t < SCAN_B) bpfx[t] = part[t] - v;  // exclusive
    if (t == SCAN_B - 1) rowptr[N_NODES] = part[t];
}

__global__ __launch_bounds__(256) void k_scan3(const int* __restrict__ deg,
                                               const int* __restrict__ bpfx,
                                               int* __restrict__ rowptr,
                                               int* __restrict__ cursor) {
    __shared__ int part[256];
    int t = threadIdx.x;
    int i = blockIdx.x * 256 + t;
    int v = (i < N_NODES) ? deg[i] : 0;
    part[t] = v;
    __syncthreads();
    for (int off = 1; off < 256; off <<= 1) {
        int u = (t >= off) ? part[t - off] : 0;
        __syncthreads();
        part[t] += u;
        __syncthreads();
    }
    if (i < N_NODES) {
        int rp = bpfx[blockIdx.x] + part[t] - v;
        rowptr[i] = rp;
        cursor[i] = rp;
    }
}

__global__ void k_fill(const int* __restrict__ src, const int* __restrict__ dst,
                       const int* __restrict__ et, int* __restrict__ cursor,
                       int* __restrict__ epack) {
    int e = blockIdx.x * blockDim.x + threadIdx.x;
    if (e < N_EDGES) {
        int slot = atomicAdd(&cursor[dst[e]], 1);
        epack[slot] = src[e] | (et[e] << 16);  // src < 50000 < 2^16
    }
}

// ---------------- weight pre-pack into MFMA B-fragment layouts (bf16) --------
// Pmsg (Wstack, K=512, N=128): frag f = nt*16 + kc (nt<8, kc<16);
//   idx = (f*64 + l)*8 + i ; k = kc*32 + (l>>4)*8 + i ; n = nt*16 + (l&15)
// Pih/Phh (K=128, N=384): frag f = nt*4 + c (nt<24); k = c*32 + (l>>4)*8 + i ; B[k][n]=W[n][k]
__global__ void k_pack(const float* __restrict__ Wmsg, const float* __restrict__ Wih,
                       const float* __restrict__ Whh, unsigned short* __restrict__ Pmsg,
                       unsigned short* __restrict__ Pih, unsigned short* __restrict__ Phh) {
    int bt = blockIdx.x;  // 0..319
    int l = threadIdx.x;  // 0..63
    if (bt < 128) {  // Pmsg frag f = bt
        int nt = bt >> 4, kc = bt & 15;
        int n = nt * 16 + (l & 15);
        unsigned short* out = Pmsg + (((size_t)bt * 64 + l) * 8);
#pragma unroll
        for (int i = 0; i < 8; ++i) {
            int k = kc * 32 + ((l >> 4) << 3) + i;
            out[i] = f2bf(Wmsg[(size_t)(k >> 7) * (D * D) + (k & 127) * D + n]);
        }
        return;
    }
    const float* src;
    unsigned short* dstp;
    int id;
    if (bt < 224) { id = bt - 128; src = Wih; dstp = Pih; }
    else          { id = bt - 224; src = Whh; dstp = Phh; }
    int nt = id >> 2, c = id & 3;
    int n = nt * 16 + (l & 15);
    unsigned short* out = dstp + (((size_t)(nt * 4 + c) * 64 + l) * 8);
#pragma unroll
    for (int i = 0; i < 8; ++i) {
        int k = c * 32 + ((l >> 4) << 3) + i;
        out[i] = f2bf(src[n * D + k]);
    }
}

// ---------------- tiny gate-bias table: gb4[col] = {br, bz, bin, bhn} -------
__global__ void k_pack_bias(const float* __restrict__ bih, const float* __restrict__ bhh,
                            float4* __restrict__ gb4) {
    int c = threadIdx.x;  // 0..127
    float4 g;
    g.x = bih[c] + bhh[c];              // r gate combined bias
    g.y = bih[128 + c] + bhh[128 + c];  // z gate combined bias
    g.z = bih[256 + c];                 // n gate input bias
    g.w = bhh[256 + c];                 // n gate hidden bias
    gb4[c] = g;
}

// ---------------- aggregate: S[v][t][d] = sum_{in-edges of type t} hbf[src][d] --
__global__ __launch_bounds__(256) void k_aggregate_s(const unsigned short* __restrict__ hbf,
                                                     const int* __restrict__ rowptr,
                                                     const int* __restrict__ epack,
                                                     unsigned short* __restrict__ S,
                                                     unsigned* __restrict__ deg4) {
    int w = threadIdx.x >> 6, l = threadIdx.x & 63;
    int v = blockIdx.x * 4 + w;
    if (v >= N_NODES) return;
    int lo = rowptr[v], hi = rowptr[v + 1];
    float a00 = 0.f, a01 = 0.f, a10 = 0.f, a11 = 0.f;
    float a20 = 0.f, a21 = 0.f, a30 = 0.f, a31 = 0.f;
    unsigned c0 = 0, c1 = 0, c2 = 0, c3 = 0;
    int i = lo;
    for (; i + 4 <= hi; i += 4) {
        int e0 = epack[i], e1 = epack[i + 1], e2 = epack[i + 2], e3 = epack[i + 3];
        unsigned x0 = *(const unsigned*)(hbf + ((size_t)(e0 & 0xFFFF) << 7) + 2 * l);
        unsigned x1 = *(const unsigned*)(hbf + ((size_t)(e1 & 0xFFFF) << 7) + 2 * l);
        unsigned x2 = *(const unsigned*)(hbf + ((size_t)(e2 & 0xFFFF) << 7) + 2 * l);
        unsigned x3 = *(const unsigned*)(hbf + ((size_t)(e3 & 0xFFFF) << 7) + 2 * l);
#define ACC_EDGE(e, x)                                                        \
        {                                                                     \
            int t_ = (e) >> 16;                                               \
            float lo_ = bf2f_u((x) & 0xFFFF), hi_ = bf2f_u((x) >> 16);        \
            if (t_ == 0)      { a00 += lo_; a01 += hi_; c0++; }               \
            else if (t_ == 1) { a10 += lo_; a11 += hi_; c1++; }               \
            else if (t_ == 2) { a20 += lo_; a21 += hi_; c2++; }               \
            else              { a30 += lo_; a31 += hi_; c3++; }               \
        }
        ACC_EDGE(e0, x0) ACC_EDGE(e1, x1) ACC_EDGE(e2, x2) ACC_EDGE(e3, x3)
    }
    for (; i < hi; ++i) {
        int e0 = epack[i];
        unsigned x0 = *(const unsigned*)(hbf + ((size_t)(e0 & 0xFFFF) << 7) + 2 * l);
        ACC_EDGE(e0, x0)
    }
#undef ACC_EDGE
    unsigned* Srow = (unsigned*)(S + (size_t)v * 512);
    Srow[l]       = (unsigned)f2bf(a00) | ((unsigned)f2bf(a01) << 16);
    Srow[64 + l]  = (unsigned)f2bf(a10) | ((unsigned)f2bf(a11) << 16);
    Srow[128 + l] = (unsigned)f2bf(a20) | ((unsigned)f2bf(a21) << 16);
    Srow[192 + l] = (unsigned)f2bf(a30) | ((unsigned)f2bf(a31) << 16);
    if (l == 0) {
        uint4v dg = {c0, c1, c2, c3};
        *(uint4v*)(deg4 + (size_t)v * 4) = dg;
    }
}

// ---------------- a-GEMM (no LDS, no barriers): abf = bf16(S@Wstack + dg-bias) --
// 4 waves x 16 rows = 64 rows/block; B-frags direct from L2; nt-pairs for ILP
__global__ __launch_bounds__(256) void k_gemm_a(const unsigned short* __restrict__ S,
                                                const unsigned short* __restrict__ Pmsg,
                                                const unsigned* __restrict__ deg4,
                                                const float* __restrict__ bmsg,
                                                unsigned short* __restrict__ abf) {
    int tid = threadIdx.x, w = tid >> 6, l = tid & 63;
    int base = blockIdx.x * 64 + w * 16;
    int lr = l & 15, kb = l >> 4;
    int arow = base + lr; if (arow >= N_NODES) arow = N_NODES - 1;
    const short8* Sr = (const short8*)(S + (size_t)arow * 512);
    short8 af[16];
#pragma unroll
    for (int kc = 0; kc < 16; ++kc) af[kc] = Sr[kc * 4 + kb];
    uint4v dg[4];
#pragma unroll
    for (int j = 0; j < 4; ++j) {
        int row = base + kb * 4 + j; if (row >= N_NODES) row = N_NODES - 1;
        dg[j] = *(const uint4v*)(deg4 + (size_t)row * 4);
    }
    const short8* Bp = (const short8*)Pmsg;  // frag f: Bp[f*64 + l]
#pragma unroll
    for (int ntp = 0; ntp < 4; ++ntp) {
        f32x4 acc0 = {0.f, 0.f, 0.f, 0.f}, acc1 = {0.f, 0.f, 0.f, 0.f};
#pragma unroll
        for (int kc = 0; kc < 16; ++kc) {
            short8 b0 = Bp[(((ntp * 2 + 0) * 16 + kc) * 64) + l];
            short8 b1 = Bp[(((ntp * 2 + 1) * 16 + kc) * 64) + l];
            acc0 = __builtin_amdgcn_mfma_f32_16x16x32_bf16(af[kc], b0, acc0, 0, 0, 0);
            acc1 = __builtin_amdgcn_mfma_f32_16x16x32_bf16(af[kc], b1, acc1, 0, 0, 0);
        }
#pragma unroll
        for (int half = 0; half < 2; ++half) {
            f32x4 acc = half ? acc1 : acc0;
            int col = (ntp * 2 + half) * 16 + lr;
            float b0 = bmsg[col], b1 = bmsg[128 + col], b2 = bmsg[256 + col], b3 = bmsg[384 + col];
#pragma unroll
            for (int j = 0; j < 4; ++j) {
                int row = base + kb * 4 + j;
                if (row < N_NODES) {
                    float bias = (float)dg[j].x * b0 + (float)dg[j].y * b1 +
                                 (float)dg[j].z * b2 + (float)dg[j].w * b3;
                    abf[(size_t)row * D + col] = f2bf(acc[j] + bias);
                }
            }
        }
    }
}

// ---------------- fused GRU (no LDS, no barriers): per-column-tile gates -----
// 4 waves x 32 rows = 128 rows/block. Per nt: r,z merged Gi+Gh acc; n split.
__global__ __launch_bounds__(256) void k_gru(const unsigned short* __restrict__ abf,
                                             unsigned short* __restrict__ hbf,
                                             const unsigned short* __restrict__ Pih,
                                             const unsigned short* __restrict__ Phh,
                                             const float4* __restrict__ gb4) {
    int tid = threadIdx.x, w = tid >> 6, l = tid & 63;
    int base = blockIdx.x * 128 + w * 32;
    int lr = l & 15, kb = l >> 4;
    short8 afa[2][4], afh[2][4];
#pragma unroll
    for (int r2 = 0; r2 < 2; ++r2) {
        int arow = base + r2 * 16 + lr; if (arow >= N_NODES) arow = N_NODES - 1;
        const short8* ar = (const short8*)(abf + (size_t)arow * D);
        const short8* hr = (const short8*)(hbf + (size_t)arow * D);
#pragma unroll
        for (int c = 0; c < 4; ++c) { afa[r2][c] = ar[c * 4 + kb]; afh[r2][c] = hr[c * 4 + kb]; }
    }
    const short8* Bi = (const short8*)Pih;  // frag f: Bi[f*64 + l], f = (p*8+nt)*4+c
    const short8* Bh = (const short8*)Phh;
#pragma unroll
    for (int nt = 0; nt < 8; ++nt) {
        f32x4 racc[2], zacc[2], giacc[2], ghacc[2];
#pragma unroll
        for (int r2 = 0; r2 < 2; ++r2) {
            racc[r2] = (f32x4){0.f, 0.f, 0.f, 0.f};
            zacc[r2] = (f32x4){0.f, 0.f, 0.f, 0.f};
            giacc[r2] = (f32x4){0.f, 0.f, 0.f, 0.f};
            ghacc[r2] = (f32x4){0.f, 0.f, 0.f, 0.f};
        }
#pragma unroll
        for (int c = 0; c < 4; ++c) {
            short8 bir = Bi[((0 * 8 + nt) * 4 + c) * 64 + l];
            short8 bhr = Bh[((0 * 8 + nt) * 4 + c) * 64 + l];
            short8 biz = Bi[((1 * 8 + nt) * 4 + c) * 64 + l];
            short8 bhz = Bh[((1 * 8 + nt) * 4 + c) * 64 + l];
            short8 bin = Bi[((2 * 8 + nt) * 4 + c) * 64 + l];
            short8 bhn = Bh[((2 * 8 + nt) * 4 + c) * 64 + l];
#pragma unroll
            for (int r2 = 0; r2 < 2; ++r2) {
                racc[r2] = __builtin_amdgcn_mfma_f32_16x16x32_bf16(afa[r2][c], bir, racc[r2], 0, 0, 0);
                racc[r2] = __builtin_amdgcn_mfma_f32_16x16x32_bf16(afh[r2][c], bhr, racc[r2], 0, 0, 0);
                zacc[r2] = __builtin_amdgcn_mfma_f32_16x16x32_bf16(afa[r2][c], biz, zacc[r2], 0, 0, 0);
                zacc[r2] = __builtin_amdgcn_mfma_f32_16x16x32_bf16(afh[r2][c], bhz, zacc[r2], 0, 0, 0);
                giacc[r2] = __builtin_amdgcn_mfma_f32_16x16x32_bf16(afa[r2][c], bin, giacc[r2], 0, 0, 0);
                ghacc[r2] = __builtin_amdgcn_mfma_f32_16x16x32_bf16(afh[r2][c], bhn, ghacc[r2], 0, 0, 0);
            }
        }
        int col = nt * 16 + lr;
        float4 gb = gb4[col];
#pragma unroll
        for (int r2 = 0; r2 < 2; ++r2) {
#pragma unroll
            for (int j = 0; j < 4; ++j) {
                int row = base + r2 * 16 + kb * 4 + j;
                if (row < N_NODES) {
                    float rr = fsigmoid(racc[r2][j] + gb.x);
                    float zz = fsigmoid(zacc[r2][j] + gb.y);
                    float nn = ftanh(giacc[r2][j] + gb.z + rr * (ghacc[r2][j] + gb.w));
                    size_t idx = (size_t)row * D + col;
                    float hold = bf2f_u(hbf[idx]);
                    hbf[idx] = f2bf((1.f - zz) * nn + zz * hold);
                }
            }
        }
    }
}

// ---------------- pool phase 1: partial row-sums (bf16 h) ----------------
__global__ __launch_bounds__(256) void k_pool1(const unsigned short* __restrict__ hbf,
                                               const int* __restrict__ counts,
                                               float* __restrict__ partial) {
    __shared__ float tmp[256];
    int g = blockIdx.x / POOL_SPLIT;
    int j = blockIdx.x % POOL_SPLIT;
    int t = threadIdx.x;
    int offset = 0;
    for (int i = 0; i < g; ++i) offset += counts[i];
    int cnt = counts[g];
    int d = t & 127, half = t >> 7;
    float acc = 0.f;
    for (int r = 2 * j + half; r < cnt; r += 2 * POOL_SPLIT)
        acc += bf2f_u(hbf[(size_t)(offset + r) * D + d]);
    tmp[t] = acc;
    __syncthreads();
    if (t < D) partial[(size_t)(g * POOL_SPLIT + j) * D + t] = tmp[t] + tmp[t + 128];
}

// ---------------- pool phase 2: combine + MLP + sigmoid ----------------
__global__ __launch_bounds__(256) void k_pool2(const float* __restrict__ partial,
                                               const int* __restrict__ counts,
                                               const float* __restrict__ W1,
                                               const float* __restrict__ b1,
                                               const float* __restrict__ W2,
                                               const float* __restrict__ b2,
                                               float* __restrict__ out) {
    __shared__ float pooled[D];
    __shared__ float xh[HID];
    int g = blockIdx.x;
    int t = threadIdx.x;
    int cnt = counts[g];
    if (t < D) {
        float s = 0.f;
#pragma unroll
        for (int j = 0; j < POOL_SPLIT; ++j)
            s += partial[(size_t)(g * POOL_SPLIT + j) * D + t];
        pooled[t] = s / (float)cnt;
    }
    __syncthreads();
    float x = b1[t];
    for (int k = 0; k < D; ++k) x += pooled[k] * W1[k * HID + t];
    x = fmaxf(x, 0.f);
    xh[t] = x * W2[t];
    __syncthreads();
    for (int s = 128; s > 0; s >>= 1) {
        if (t < s) xh[t] += xh[t + s];
        __syncthreads();
    }
    if (t == 0) out[g] = 1.f / (1.f + __expf(-(xh[0] + b2[0])));
}

extern "C" void kernel_launch(void* const* d_in, const int* in_sizes, int n_in,
                              void* d_out, int out_size, void* d_ws, size_t ws_size,
                              hipStream_t stream) {
    const float* nf   = (const float*)d_in[0];
    const int* esrc   = (const int*)d_in[1];
    const int* edst   = (const int*)d_in[2];
    const int* etyp   = (const int*)d_in[3];
    const int* counts = (const int*)d_in[4];
    const float* Wmsg = (const float*)d_in[5];
    const float* bmsg = (const float*)d_in[6];   // [4][128] flat == [512] concat
    const float* Wih  = (const float*)d_in[7];
    const float* Whh  = (const float*)d_in[8];
    const float* bih  = (const float*)d_in[9];
    const float* bhh  = (const float*)d_in[10];
    const float* W1   = (const float*)d_in[11];
    const float* b1   = (const float*)d_in[12];
    const float* W2   = (const float*)d_in[13];
    const float* b2   = (const float*)d_in[14];
    float* out = (float*)d_out;

    char* ws = (char*)d_ws;
    size_t off = 0;
    auto alloc = [&](size_t bytes) {
        void* p = ws + off;
        off = (off + bytes + 255) & ~(size_t)255;
        return p;
    };
    unsigned short* hbf = (unsigned short*)alloc((size_t)N_NODES * D * 2);
    unsigned short* abf = (unsigned short*)alloc((size_t)N_NODES * D * 2);
    unsigned short* S   = (unsigned short*)alloc((size_t)N_NODES * 512 * 2);
    unsigned short* Pmsg = (unsigned short*)alloc(128 * 64 * 8 * 2);
    unsigned short* Pih  = (unsigned short*)alloc(24 * 4 * 64 * 8 * 2);
    unsigned short* Phh  = (unsigned short*)alloc(24 * 4 * 64 * 8 * 2);
    float* gb4 = (float*)alloc(128 * 16);
    int* deg    = (int*)alloc((size_t)N_NODES * 4);
    unsigned* deg4 = (unsigned*)alloc((size_t)N_NODES * 16);
    int* rowptr = (int*)alloc((size_t)(N_NODES + 1) * 4);
    int* cursor = (int*)alloc((size_t)N_NODES * 4);
    int* epack  = (int*)alloc((size_t)N_EDGES * 4);
    float* partial = (float*)alloc((size_t)B_GRAPHS * POOL_SPLIT * D * 4);
    int* bsum = (int*)alloc(SCAN_B * 4);
    int* bpfx = (int*)alloc(SCAN_B * 4);

    hipMemsetAsync(deg, 0, (size_t)N_NODES * 4, stream);
    k_init_h<<<(N_NODES * D) / 256, 256, 0, stream>>>(nf, hbf);
    k_hist<<<N_EDGES / 256, 256, 0, stream>>>(edst, deg);
    k_scan1<<<SCAN_B, 256, 0, stream>>>(deg, bsum);
    k_scan2<<<1, 256, 0, stream>>>(bsum, bpfx, rowptr);
    k_scan3<<<SCAN_B, 256, 0, stream>>>(deg, bpfx, rowptr, cursor);
    k_fill<<<N_EDGES / 256, 256, 0, stream>>>(esrc, edst, etyp, cursor, epack);
    k_pack<<<320, 64, 0, stream>>>(Wmsg, Wih, Whh, Pmsg, Pih, Phh);
    k_pack_bias<<<1, 128, 0, stream>>>(bih, bhh, (float4*)gb4);

    int ga_blocks  = (N_NODES + 63) / 64;    // 782
    int gru_blocks = (N_NODES + 127) / 128;  // 391
    int agg_blocks = (N_NODES + 3) / 4;      // 12500
    for (int s = 0; s < N_STEPS; ++s) {
        k_aggregate_s<<<agg_blocks, 256, 0, stream>>>(hbf, rowptr, epack, S, deg4);
        k_gemm_a<<<ga_blocks, 256, 0, stream>>>(S, Pmsg, deg4, bmsg, abf);
        k_gru<<<gru_blocks, 256, 0, stream>>>(abf, hbf, Pih, Phh, (const float4*)gb4);
    }
    k_pool1<<<B_GRAPHS * POOL_SPLIT, 256, 0, stream>>>(hbf, counts, partial);
    k_pool2<<<B_GRAPHS, 256, 0, stream>>>(partial, counts, W1, b1, W2, b2, out);
}

// Round 7
// 1064.555 us; speedup vs baseline: 6.2409x; 1.0088x over previous
//
#include <hip/hip_runtime.h>
#include <hip/hip_bf16.h>

#define N_NODES 50000
#define N_EDGES 800000
#define D 128
#define N_ETYPES 4
#define N_STEPS 8
#define B_GRAPHS 50
#define HID 256
#define POOL_SPLIT 16
#define SCAN_B 196  // ceil(50000/256)

typedef __attribute__((ext_vector_type(8))) short short8;
typedef __attribute__((ext_vector_type(4))) float f32x4;
typedef __attribute__((ext_vector_type(4))) unsigned uint4v;

static __device__ __forceinline__ unsigned short f2bf(float f) {
    union { float f; unsigned u; } v; v.f = f;
    unsigned r = v.u + 0x7FFF + ((v.u >> 16) & 1);
    return (unsigned short)(r >> 16);
}
static __device__ __forceinline__ float bf2f_u(unsigned s) {  // low 16 bits
    union { unsigned u; float f; } v; v.u = s << 16;
    return v.f;
}
static __device__ __forceinline__ float fsigmoid(float x) {
    return 1.f / (1.f + __expf(-x));
}
static __device__ __forceinline__ float ftanh(float x) {
    return 2.f / (1.f + __expf(-2.f * x)) - 1.f;
}

// ---------------- init: h_bf = bf16(node_features) ----------------
__global__ void k_init_h(const float* __restrict__ nf, unsigned short* __restrict__ hbf) {
    int i = blockIdx.x * blockDim.x + threadIdx.x;
    if (i < N_NODES * D) hbf[i] = f2bf(nf[i]);
}

// ---------------- CSR build ----------------
__global__ void k_hist(const int* __restrict__ dst, int* __restrict__ deg) {
    int e = blockIdx.x * blockDim.x + threadIdx.x;
    if (e < N_EDGES) atomicAdd(&deg[dst[e]], 1);
}

__global__ __launch_bounds__(256) void k_scan1(const int* __restrict__ deg,
                                               int* __restrict__ bsum) {
    __shared__ int tmp[256];
    int t = threadIdx.x;
    int i = blockIdx.x * 256 + t;
    tmp[t] = (i < N_NODES) ? deg[i] : 0;
    __syncthreads();
    for (int s = 128; s > 0; s >>= 1) {
        if (t < s) tmp[t] += tmp[t + s];
        __syncthreads();
    }
    if (t == 0) bsum[blockIdx.x] = tmp[0];
}

__global__ __launch_bounds__(256) void k_scan2(const int* __restrict__ bsum,
                                               int* __restrict__ bpfx,
                                               int* __restrict__ rowptr) {
    __shared__ int part[256];
    int t = threadIdx.x;
    int v = (t < SCAN_B) ? bsum[t] : 0;
    part[t] = v;
    __syncthreads();
    for (int off = 1; off < 256; off <<= 1) {
        int u = (t >= off) ? part[t - off] : 0;
        __syncthreads();
        part[t] += u;
        __syncthreads();
    }
    if (t < SCAN_B) bpfx[t] = part[t] - v;  // exclusive
    if (t == SCAN_B - 1) rowptr[N_NODES] = part[t];
}

__global__ __launch_bounds__(256) void k_scan3(const int* __restrict__ deg,
                                               const int* __restrict__ bpfx,
                                               int* __restrict__ rowptr,
                                               int* __restrict__ cursor) {
    __shared__ int part[256];
    int t = threadIdx.x;
    int i = blockIdx.x * 256 + t;
    int v = (i < N_NODES) ? deg[i] : 0;
    part[t] = v;
    __syncthreads();
    for (int off = 1; off < 256; off <<= 1) {
        int u = (t >= off) ? part[t - off] : 0;
        __syncthreads();
        part[t] += u;
        __syncthreads();
    }
    if (i < N_NODES) {
        int rp = bpfx[blockIdx.x] + part[t] - v;
        rowptr[i] = rp;
        cursor[i] = rp;
    }
}

__global__ void k_fill(const int* __restrict__ src, const int* __restrict__ dst,
                       const int* __restrict__ et, int* __restrict__ cursor,
                       int* __restrict__ epack) {
    int e = blockIdx.x * blockDim.x + threadIdx.x;
    if (e < N_EDGES) {
        int slot = atomicAdd(&cursor[dst[e]], 1);
        epack[slot] = src[e] | (et[e] << 16);  // src < 50000 < 2^16
    }
}

// ---------------- weight pre-pack into MFMA B-fragment layouts (bf16) --------
// Pmsg (Wstack, K=512, N=128): frag f = nt*16 + kc (nt<8, kc<16);
//   idx = (f*64 + l)*8 + i ; k = kc*32 + (l>>4)*8 + i ; n = nt*16 + (l&15)
// Pih/Phh (K=128, N=384): frag f = nt*4 + c (nt<24); k = c*32 + (l>>4)*8 + i ; B[k][n]=W[n][k]
__global__ void k_pack(const float* __restrict__ Wmsg, const float* __restrict__ Wih,
                       const float* __restrict__ Whh, unsigned short* __restrict__ Pmsg,
                       unsigned short* __restrict__ Pih, unsigned short* __restrict__ Phh) {
    int bt = blockIdx.x;  // 0..319
    int l = threadIdx.x;  // 0..63
    if (bt < 128) {  // Pmsg frag f = bt
        int nt = bt >> 4, kc = bt & 15;
        int n = nt * 16 + (l & 15);
        unsigned short* out = Pmsg + (((size_t)bt * 64 + l) * 8);
#pragma unroll
        for (int i = 0; i < 8; ++i) {
            int k = kc * 32 + ((l >> 4) << 3) + i;
            out[i] = f2bf(Wmsg[(size_t)(k >> 7) * (D * D) + (k & 127) * D + n]);
        }
        return;
    }
    const float* src;
    unsigned short* dstp;
    int id;
    if (bt < 224) { id = bt - 128; src = Wih; dstp = Pih; }
    else          { id = bt - 224; src = Whh; dstp = Phh; }
    int nt = id >> 2, c = id & 3;
    int n = nt * 16 + (l & 15);
    unsigned short* out = dstp + (((size_t)(nt * 4 + c) * 64 + l) * 8);
#pragma unroll
    for (int i = 0; i < 8; ++i) {
        int k = c * 32 + ((l >> 4) << 3) + i;
        out[i] = f2bf(src[n * D + k]);
    }
}

// ---------------- tiny gate-bias table: gb4[col] = {br, bz, bin, bhn} -------
__global__ void k_pack_bias(const float* __restrict__ bih, const float* __restrict__ bhh,
                            float4* __restrict__ gb4) {
    int c = threadIdx.x;  // 0..127
    float4 g;
    g.x = bih[c] + bhh[c];              // r gate combined bias
    g.y = bih[128 + c] + bhh[128 + c];  // z gate combined bias
    g.z = bih[256 + c];                 // n gate input bias
    g.w = bhh[256 + c];                 // n gate hidden bias
    gb4[c] = g;
}

// ---------------- aggregate: S[v][t][d] = sum_{in-edges of type t} hbf[src][d] --
__global__ __launch_bounds__(256) void k_aggregate_s(const unsigned short* __restrict__ hbf,
                                                     const int* __restrict__ rowptr,
                                                     const int* __restrict__ epack,
                                                     unsigned short* __restrict__ S,
                                                     unsigned* __restrict__ deg4) {
    int w = threadIdx.x >> 6, l = threadIdx.x & 63;
    int v = blockIdx.x * 4 + w;
    if (v >= N_NODES) return;
    int lo = rowptr[v], hi = rowptr[v + 1];
    float a00 = 0.f, a01 = 0.f, a10 = 0.f, a11 = 0.f;
    float a20 = 0.f, a21 = 0.f, a30 = 0.f, a31 = 0.f;
    unsigned c0 = 0, c1 = 0, c2 = 0, c3 = 0;
    int i = lo;
    for (; i + 4 <= hi; i += 4) {
        int e0 = epack[i], e1 = epack[i + 1], e2 = epack[i + 2], e3 = epack[i + 3];
        unsigned x0 = *(const unsigned*)(hbf + ((size_t)(e0 & 0xFFFF) << 7) + 2 * l);
        unsigned x1 = *(const unsigned*)(hbf + ((size_t)(e1 & 0xFFFF) << 7) + 2 * l);
        unsigned x2 = *(const unsigned*)(hbf + ((size_t)(e2 & 0xFFFF) << 7) + 2 * l);
        unsigned x3 = *(const unsigned*)(hbf + ((size_t)(e3 & 0xFFFF) << 7) + 2 * l);
#define ACC_EDGE(e, x)                                                        \
        {                                                                     \
            int t_ = (e) >> 16;                                               \
            float lo_ = bf2f_u((x) & 0xFFFF), hi_ = bf2f_u((x) >> 16);        \
            if (t_ == 0)      { a00 += lo_; a01 += hi_; c0++; }               \
            else if (t_ == 1) { a10 += lo_; a11 += hi_; c1++; }               \
            else if (t_ == 2) { a20 += lo_; a21 += hi_; c2++; }               \
            else              { a30 += lo_; a31 += hi_; c3++; }               \
        }
        ACC_EDGE(e0, x0) ACC_EDGE(e1, x1) ACC_EDGE(e2, x2) ACC_EDGE(e3, x3)
    }
    for (; i < hi; ++i) {
        int e0 = epack[i];
        unsigned x0 = *(const unsigned*)(hbf + ((size_t)(e0 & 0xFFFF) << 7) + 2 * l);
        ACC_EDGE(e0, x0)
    }
#undef ACC_EDGE
    unsigned* Srow = (unsigned*)(S + (size_t)v * 512);
    Srow[l]       = (unsigned)f2bf(a00) | ((unsigned)f2bf(a01) << 16);
    Srow[64 + l]  = (unsigned)f2bf(a10) | ((unsigned)f2bf(a11) << 16);
    Srow[128 + l] = (unsigned)f2bf(a20) | ((unsigned)f2bf(a21) << 16);
    Srow[192 + l] = (unsigned)f2bf(a30) | ((unsigned)f2bf(a31) << 16);
    if (l == 0) {
        uint4v dg = {c0, c1, c2, c3};
        *(uint4v*)(deg4 + (size_t)v * 4) = dg;
    }
}

// ---------------- a-GEMM (no LDS, no barriers): abf = bf16(S@Wstack + dg-bias) --
// 4 waves x 16 rows = 64 rows/block; B-frags direct from L2; nt-pairs for ILP
__global__ __launch_bounds__(256) void k_gemm_a(const unsigned short* __restrict__ S,
                                                const unsigned short* __restrict__ Pmsg,
                                                const unsigned* __restrict__ deg4,
                                                const float* __restrict__ bmsg,
                                                unsigned short* __restrict__ abf) {
    int tid = threadIdx.x, w = tid >> 6, l = tid & 63;
    int base = blockIdx.x * 64 + w * 16;
    int lr = l & 15, kb = l >> 4;
    int arow = base + lr; if (arow >= N_NODES) arow = N_NODES - 1;
    const short8* Sr = (const short8*)(S + (size_t)arow * 512);
    short8 af[16];
#pragma unroll
    for (int kc = 0; kc < 16; ++kc) af[kc] = Sr[kc * 4 + kb];
    uint4v dg[4];
#pragma unroll
    for (int j = 0; j < 4; ++j) {
        int row = base + kb * 4 + j; if (row >= N_NODES) row = N_NODES - 1;
        dg[j] = *(const uint4v*)(deg4 + (size_t)row * 4);
    }
    const short8* Bp = (const short8*)Pmsg;  // frag f: Bp[f*64 + l]
#pragma unroll
    for (int ntp = 0; ntp < 4; ++ntp) {
        f32x4 acc0 = {0.f, 0.f, 0.f, 0.f}, acc1 = {0.f, 0.f, 0.f, 0.f};
#pragma unroll
        for (int kc = 0; kc < 16; ++kc) {
            short8 b0 = Bp[(((ntp * 2 + 0) * 16 + kc) * 64) + l];
            short8 b1 = Bp[(((ntp * 2 + 1) * 16 + kc) * 64) + l];
            acc0 = __builtin_amdgcn_mfma_f32_16x16x32_bf16(af[kc], b0, acc0, 0, 0, 0);
            acc1 = __builtin_amdgcn_mfma_f32_16x16x32_bf16(af[kc], b1, acc1, 0, 0, 0);
        }
#pragma unroll
        for (int half = 0; half < 2; ++half) {
            f32x4 acc = half ? acc1 : acc0;
            int col = (ntp * 2 + half) * 16 + lr;
            float b0 = bmsg[col], b1 = bmsg[128 + col], b2 = bmsg[256 + col], b3 = bmsg[384 + col];
#pragma unroll
            for (int j = 0; j < 4; ++j) {
                int row = base + kb * 4 + j;
                if (row < N_NODES) {
                    float bias = (float)dg[j].x * b0 + (float)dg[j].y * b1 +
                                 (float)dg[j].z * b2 + (float)dg[j].w * b3;
                    abf[(size_t)row * D + col] = f2bf(acc[j] + bias);
                }
            }
        }
    }
}

// ---------------- fused GRU (no LDS, no barriers), HIGH-GRID version --------
// Block = 64 rows x 64 cols: 4 waves x 16 rows; col-half = (bid&1)*4 ntiles.
// Grid = 2 * ceil(N/64) = 1564 blocks -> ~6 blocks/CU, ~24 waves/CU.
__global__ __launch_bounds__(256) void k_gru(const unsigned short* __restrict__ abf,
                                             unsigned short* __restrict__ hbf,
                                             const unsigned short* __restrict__ Pih,
                                             const unsigned short* __restrict__ Phh,
                                             const float4* __restrict__ gb4) {
    int tid = threadIdx.x, w = tid >> 6, l = tid & 63;
    int base = (blockIdx.x >> 1) * 64 + w * 16;
    int nt0 = (blockIdx.x & 1) * 4;
    int lr = l & 15, kb = l >> 4;
    int arow = base + lr; if (arow >= N_NODES) arow = N_NODES - 1;
    const short8* ar = (const short8*)(abf + (size_t)arow * D);
    const short8* hr = (const short8*)(hbf + (size_t)arow * D);
    short8 afa[4], afh[4];
#pragma unroll
    for (int c = 0; c < 4; ++c) { afa[c] = ar[c * 4 + kb]; afh[c] = hr[c * 4 + kb]; }
    const short8* Bi = (const short8*)Pih;  // frag f: Bi[f*64 + l], f = (p*8+nt)*4+c
    const short8* Bh = (const short8*)Phh;
#pragma unroll
    for (int ntl = 0; ntl < 4; ++ntl) {
        int nt = nt0 + ntl;
        f32x4 racc = {0.f, 0.f, 0.f, 0.f};
        f32x4 zacc = {0.f, 0.f, 0.f, 0.f};
        f32x4 giacc = {0.f, 0.f, 0.f, 0.f};
        f32x4 ghacc = {0.f, 0.f, 0.f, 0.f};
#pragma unroll
        for (int c = 0; c < 4; ++c) {
            short8 bir = Bi[((0 * 8 + nt) * 4 + c) * 64 + l];
            short8 bhr = Bh[((0 * 8 + nt) * 4 + c) * 64 + l];
            short8 biz = Bi[((1 * 8 + nt) * 4 + c) * 64 + l];
            short8 bhz = Bh[((1 * 8 + nt) * 4 + c) * 64 + l];
            short8 bin = Bi[((2 * 8 + nt) * 4 + c) * 64 + l];
            short8 bhn = Bh[((2 * 8 + nt) * 4 + c) * 64 + l];
            racc = __builtin_amdgcn_mfma_f32_16x16x32_bf16(afa[c], bir, racc, 0, 0, 0);
            racc = __builtin_amdgcn_mfma_f32_16x16x32_bf16(afh[c], bhr, racc, 0, 0, 0);
            zacc = __builtin_amdgcn_mfma_f32_16x16x32_bf16(afa[c], biz, zacc, 0, 0, 0);
            zacc = __builtin_amdgcn_mfma_f32_16x16x32_bf16(afh[c], bhz, zacc, 0, 0, 0);
            giacc = __builtin_amdgcn_mfma_f32_16x16x32_bf16(afa[c], bin, giacc, 0, 0, 0);
            ghacc = __builtin_amdgcn_mfma_f32_16x16x32_bf16(afh[c], bhn, ghacc, 0, 0, 0);
        }
        int col = nt * 16 + lr;
        float4 gb = gb4[col];
#pragma unroll
        for (int j = 0; j < 4; ++j) {
            int row = base + kb * 4 + j;
            if (row < N_NODES) {
                float rr = fsigmoid(racc[j] + gb.x);
                float zz = fsigmoid(zacc[j] + gb.y);
                float nn = ftanh(giacc[j] + gb.z + rr * (ghacc[j] + gb.w));
                size_t idx = (size_t)row * D + col;
                float hold = bf2f_u(hbf[idx]);
                hbf[idx] = f2bf((1.f - zz) * nn + zz * hold);
            }
        }
    }
}

// ---------------- pool phase 1: partial row-sums (bf16 h) ----------------
__global__ __launch_bounds__(256) void k_pool1(const unsigned short* __restrict__ hbf,
                                               const int* __restrict__ counts,
                                               float* __restrict__ partial) {
    __shared__ float tmp[256];
    int g = blockIdx.x / POOL_SPLIT;
    int j = blockIdx.x % POOL_SPLIT;
    int t = threadIdx.x;
    int offset = 0;
    for (int i = 0; i < g; ++i) offset += counts[i];
    int cnt = counts[g];
    int d = t & 127, half = t >> 7;
    float acc = 0.f;
    for (int r = 2 * j + half; r < cnt; r += 2 * POOL_SPLIT)
        acc += bf2f_u(hbf[(size_t)(offset + r) * D + d]);
    tmp[t] = acc;
    __syncthreads();
    if (t < D) partial[(size_t)(g * POOL_SPLIT + j) * D + t] = tmp[t] + tmp[t + 128];
}

// ---------------- pool phase 2: combine + MLP + sigmoid ----------------
__global__ __launch_bounds__(256) void k_pool2(const float* __restrict__ partial,
                                               const int* __restrict__ counts,
                                               const float* __restrict__ W1,
                                               const float* __restrict__ b1,
                                               const float* __restrict__ W2,
                                               const float* __restrict__ b2,
                                               float* __restrict__ out) {
    __shared__ float pooled[D];
    __shared__ float xh[HID];
    int g = blockIdx.x;
    int t = threadIdx.x;
    int cnt = counts[g];
    if (t < D) {
        float s = 0.f;
#pragma unroll
        for (int j = 0; j < POOL_SPLIT; ++j)
            s += partial[(size_t)(g * POOL_SPLIT + j) * D + t];
        pooled[t] = s / (float)cnt;
    }
    __syncthreads();
    float x = b1[t];
    for (int k = 0; k < D; ++k) x += pooled[k] * W1[k * HID + t];
    x = fmaxf(x, 0.f);
    xh[t] = x * W2[t];
    __syncthreads();
    for (int s = 128; s > 0; s >>= 1) {
        if (t < s) xh[t] += xh[t + s];
        __syncthreads();
    }
    if (t == 0) out[g] = 1.f / (1.f + __expf(-(xh[0] + b2[0])));
}

extern "C" void kernel_launch(void* const* d_in, const int* in_sizes, int n_in,
                              void* d_out, int out_size, void* d_ws, size_t ws_size,
                              hipStream_t stream) {
    const float* nf   = (const float*)d_in[0];
    const int* esrc   = (const int*)d_in[1];
    const int* edst   = (const int*)d_in[2];
    const int* etyp   = (const int*)d_in[3];
    const int* counts = (const int*)d_in[4];
    const float* Wmsg = (const float*)d_in[5];
    const float* bmsg = (const float*)d_in[6];   // [4][128] flat == [512] concat
    const float* Wih  = (const float*)d_in[7];
    const float* Whh  = (const float*)d_in[8];
    const float* bih  = (const float*)d_in[9];
    const float* bhh  = (const float*)d_in[10];
    const float* W1   = (const float*)d_in[11];
    const float* b1   = (const float*)d_in[12];
    const float* W2   = (const float*)d_in[13];
    const float* b2   = (const float*)d_in[14];
    float* out = (float*)d_out;

    char* ws = (char*)d_ws;
    size_t off = 0;
    auto alloc = [&](size_t bytes) {
        void* p = ws + off;
        off = (off + bytes + 255) & ~(size_t)255;
        return p;
    };
    unsigned short* hbf = (unsigned short*)alloc((size_t)N_NODES * D * 2);
    unsigned short* abf = (unsigned short*)alloc((size_t)N_NODES * D * 2);
    unsigned short* S   = (unsigned short*)alloc((size_t)N_NODES * 512 * 2);
    unsigned short* Pmsg = (unsigned short*)alloc(128 * 64 * 8 * 2);
    unsigned short* Pih  = (unsigned short*)alloc(24 * 4 * 64 * 8 * 2);
    unsigned short* Phh  = (unsigned short*)alloc(24 * 4 * 64 * 8 * 2);
    float* gb4 = (float*)alloc(128 * 16);
    int* deg    = (int*)alloc((size_t)N_NODES * 4);
    unsigned* deg4 = (unsigned*)alloc((size_t)N_NODES * 16);
    int* rowptr = (int*)alloc((size_t)(N_NODES + 1) * 4);
    int* cursor = (int*)alloc((size_t)N_NODES * 4);
    int* epack  = (int*)alloc((size_t)N_EDGES * 4);
    float* partial = (float*)alloc((size_t)B_GRAPHS * POOL_SPLIT * D * 4);
    int* bsum = (int*)alloc(SCAN_B * 4);
    int* bpfx = (int*)alloc(SCAN_B * 4);

    hipMemsetAsync(deg, 0, (size_t)N_NODES * 4, stream);
    k_init_h<<<(N_NODES * D) / 256, 256, 0, stream>>>(nf, hbf);
    k_hist<<<N_EDGES / 256, 256, 0, stream>>>(edst, deg);
    k_scan1<<<SCAN_B, 256, 0, stream>>>(deg, bsum);
    k_scan2<<<1, 256, 0, stream>>>(bsum, bpfx, rowptr);
    k_scan3<<<SCAN_B, 256, 0, stream>>>(deg, bpfx, rowptr, cursor);
    k_fill<<<N_EDGES / 256, 256, 0, stream>>>(esrc, edst, etyp, cursor, epack);
    k_pack<<<320, 64, 0, stream>>>(Wmsg, Wih, Whh, Pmsg, Pih, Phh);
    k_pack_bias<<<1, 128, 0, stream>>>(bih, bhh, (float4*)gb4);

    int ga_blocks  = (N_NODES + 63) / 64;        // 782
    int gru_blocks = 2 * ((N_NODES + 63) / 64);  // 1564 (64 rows x 64 cols each)
    int agg_blocks = (N_NODES + 3) / 4;          // 12500
    for (int s = 0; s < N_STEPS; ++s) {
        k_aggregate_s<<<agg_blocks, 256, 0, stream>>>(hbf, rowptr, epack, S, deg4);
        k_gemm_a<<<ga_blocks, 256, 0, stream>>>(S, Pmsg, deg4, bmsg, abf);
        k_gru<<<gru_blocks, 256, 0, stream>>>(abf, hbf, Pih, Phh, (const float4*)gb4);
    }
    k_pool1<<<B_GRAPHS * POOL_SPLIT, 256, 0, stream>>>(hbf, counts, partial);
    k_pool2<<<B_GRAPHS, 256, 0, stream>>>(partial, counts, W1, b1, W2, b2, out);
}